// Round 7
// baseline (137.557 us; speedup 1.0000x reference)
//
#include <hip/hip_runtime.h>
#include <math.h>

#define NPTS 65536
#define NV 6890
#define NT 432               // vertex tiles of 16 (432*16 = 6912 >= 6890)
#define NTPAD 8              // sentinel tiles appended for unclamped prefetch
#define VSPLIT 4             // waves per block, splitting the vertex range
#define TILES_PER_WAVE (NT / VSPLIT)   // 108  (fits in 7 bits)
#define NJ 24
#define PTS_PER_BLK 32
#define NBLK (NPTS / PTS_PER_BLK)      // 2048

typedef double f64x4 __attribute__((ext_vector_type(4)));

// Prep: pack the B-fragment stream for v_mfma_f64_16x16x4_f64.
// frag[t*64 + l] = component (l>>4) of vertex (t*16 + (l&15));
// components: 0..2 = x,y,z (f64), 3 = ||v||^2 (exact f64 from f32 coords).
// Sentinel verts (j >= NV, incl. pad tiles): (0,0,0,1e300) -> never selected.
__global__ void prep_frags_k(const float* __restrict__ verts, double* __restrict__ bf) {
    int e = blockIdx.x * blockDim.x + threadIdx.x;
    if (e >= (NT + NTPAD) * 64) return;
    int l = e & 63;
    int t = e >> 6;
    int j = t * 16 + (l & 15);
    int k = l >> 4;
    double val;
    if (j < NV) {
        if (k < 3) {
            val = (double)verts[3 * j + k];
        } else {
            double x = (double)verts[3 * j + 0];
            double y = (double)verts[3 * j + 1];
            double z = (double)verts[3 * j + 2];
            val = x * x + y * y + z * z;
        }
    } else {
        val = (k == 3) ? 1e300 : 0.0;
    }
    bf[e] = val;
}

// Pack 7-bit local tile index into the low 8 mantissa bits of the score.
// Perturbation <= 256 ulp (~1e-13 rel) << NN gap scale (~1e-3): ordering safe.
__device__ __forceinline__ double packdt(double d, int t) {
    unsigned long long u = __double_as_longlong(d);
    u = (u & ~0xFFULL) | (unsigned long long)(unsigned)t;
    return __longlong_as_double(u);
}

__launch_bounds__(256)
__global__ void smplnn_main(const float* __restrict__ xyz,
                            const float* __restrict__ rot,
                            const double* __restrict__ bf,
                            const float* __restrict__ sw,
                            const float* __restrict__ bt,
                            float* __restrict__ out) {
    // per-wave packed-score boards: [wave][set][row][col]
    __shared__ double smin[VSPLIT][2][16][16];

    const int tid  = threadIdx.x;
    const int lane = tid & 63;
    const int wave = tid >> 6;         // vertex-split id
    const int r = lane & 15;           // M/N index within fragment
    const int k = lane >> 4;           // K index (0..3)
    const int pbase = blockIdx.x * PTS_PER_BLK;

    // A fragments (same 32 points for all 4 waves):
    // A[i][k] = (-2x_i, -2y_i, -2z_i, 1.0), i = lane&15
    double a0 = (k == 3) ? 1.0 : -2.0 * (double)xyz[3 * (pbase + r) + k];
    double a1 = (k == 3) ? 1.0 : -2.0 * (double)xyz[3 * (pbase + 16 + r) + k];

    const f64x4 zero = {0.0, 0.0, 0.0, 0.0};

    // Layout self-calibration: D = row-index and D = col-index, so the
    // (lane,reg)->(row,col) mapping of the D fragment never has to be assumed.
    double ar  = (k == 3) ? (double)r : 0.0;  // A[i][3] = i  /  B[3][j] = j
    double one = (k == 3) ? 1.0 : 0.0;        // A[i][3] = 1  /  B[3][j] = 1
    f64x4 drow = __builtin_amdgcn_mfma_f64_16x16x4f64(ar, one, zero, 0, 0, 0);
    f64x4 dcol = __builtin_amdgcn_mfma_f64_16x16x4f64(one, ar, zero, 0, 0, 0);
    int rowid[4], colid[4];
    #pragma unroll
    for (int v = 0; v < 4; ++v) { rowid[v] = (int)drow[v]; colid[v] = (int)dcol[v]; }

    double m0[4], m1[4];
    #pragma unroll
    for (int v = 0; v < 4; ++v) { m0[v] = 1e301; m1[v] = 1e301; }

    // scan my quarter of the tiles: s = -2 x.v + ||v||^2, exact f64 MFMA;
    // packed-min argmin tracking (3 VALU ops per slot).
    const int tbase = wave * TILES_PER_WAVE;
    const double* bl = bf + (size_t)tbase * 64 + lane;
    double bcur = bl[0];
    #pragma unroll 4
    for (int t = 0; t < TILES_PER_WAVE; ++t) {
        double bnext = bl[(size_t)(t + 1) * 64];   // unclamped: pad tiles are sentinels
        f64x4 d0 = __builtin_amdgcn_mfma_f64_16x16x4f64(a0, bcur, zero, 0, 0, 0);
        f64x4 d1 = __builtin_amdgcn_mfma_f64_16x16x4f64(a1, bcur, zero, 0, 0, 0);
        #pragma unroll
        for (int v = 0; v < 4; ++v) {
            m0[v] = fmin(m0[v], packdt(d0[v], t));
            m1[v] = fmin(m1[v], packdt(d1[v], t));
        }
        bcur = bnext;
    }

    // publish packed slots
    #pragma unroll
    for (int v = 0; v < 4; ++v) {
        smin[wave][0][rowid[v]][colid[v]] = m0[v];
        smin[wave][1][rowid[v]][colid[v]] = m1[v];
    }
    __syncthreads();

    // epilogue: wave 0, lane 0..31 -> point (set = lane>>4, row = lane&15)
    if (wave != 0 || lane >= 32) return;
    const int set  = lane >> 4;
    const int prow = lane & 15;
    const int i = pbase + set * 16 + prow;

    // merge 4 wave-boards x 16 cols (strict < : first (w,c) wins on exact tie)
    double best = 1e302;
    int bw = 0, bc = 0;
    #pragma unroll
    for (int w = 0; w < VSPLIT; ++w) {
        #pragma unroll
        for (int c = 0; c < 16; ++c) {
            double bv = smin[w][set][prow][c];
            if (bv < best) { best = bv; bw = w; bc = c; }
        }
    }
    const int tl = (int)(__double_as_longlong(best) & 0xFFULL);
    const int bi = (bw * TILES_PER_WAVE + tl) * 16 + bc;

    const float xf = xyz[3 * i + 0];
    const float yf = xyz[3 * i + 1];
    const float zf = xyz[3 * i + 2];

    // T_fwd = W[bi] @ bone_transforms(24x16)
    const float* W = &sw[bi * NJ];
    float Tm[16];
    #pragma unroll
    for (int q = 0; q < 16; ++q) Tm[q] = 0.0f;
    #pragma unroll
    for (int kk = 0; kk < NJ; ++kk) {
        float w = W[kk];
        #pragma unroll
        for (int q = 0; q < 16; ++q) Tm[q] = fmaf(w, bt[16 * kk + q], Tm[q]);
    }

    // x_bar = T[:3,:3] @ x + T[:3,3]
    float xb0 = Tm[0] * xf + Tm[1] * yf + Tm[2]  * zf + Tm[3];
    float xb1 = Tm[4] * xf + Tm[5] * yf + Tm[6]  * zf + Tm[7];
    float xb2 = Tm[8] * xf + Tm[9] * yf + Tm[10] * zf + Tm[11];

    // rotation_hat from quaternion (r,x,y,z), normalized
    float qr = rot[4 * i + 0];
    float qx = rot[4 * i + 1];
    float qy = rot[4 * i + 2];
    float qz = rot[4 * i + 3];
    float inv = 1.0f / sqrtf(qr * qr + qx * qx + qy * qy + qz * qz);
    qr *= inv; qx *= inv; qy *= inv; qz *= inv;

    float Rh[9];
    Rh[0] = 1.0f - 2.0f * (qy * qy + qz * qz);
    Rh[1] = 2.0f * (qx * qy - qr * qz);
    Rh[2] = 2.0f * (qx * qz + qr * qy);
    Rh[3] = 2.0f * (qx * qy + qr * qz);
    Rh[4] = 1.0f - 2.0f * (qx * qx + qz * qz);
    Rh[5] = 2.0f * (qy * qz - qr * qx);
    Rh[6] = 2.0f * (qx * qz - qr * qy);
    Rh[7] = 2.0f * (qy * qz + qr * qx);
    Rh[8] = 1.0f - 2.0f * (qx * qx + qy * qy);

    // rotation_bar = T[:3,:3] @ Rh
    float RB[9];
    #pragma unroll
    for (int rr = 0; rr < 3; ++rr) {
        #pragma unroll
        for (int cc = 0; cc < 3; ++cc) {
            RB[3 * rr + cc] = Tm[4 * rr + 0] * Rh[cc]
                            + Tm[4 * rr + 1] * Rh[3 + cc]
                            + Tm[4 * rr + 2] * Rh[6 + cc];
        }
    }

    // outputs: x_bar [NPTS*3] | rotation_bar [NPTS*9] | T_fwd [NPTS*16]
    out[3 * i + 0] = xb0;
    out[3 * i + 1] = xb1;
    out[3 * i + 2] = xb2;
    float* ob = out + 3 * NPTS + 9 * i;
    #pragma unroll
    for (int q = 0; q < 9; ++q) ob[q] = RB[q];
    float* ot = out + 12 * NPTS + 16 * i;
    #pragma unroll
    for (int q = 0; q < 16; ++q) ot[q] = Tm[q];
}

extern "C" void kernel_launch(void* const* d_in, const int* in_sizes, int n_in,
                              void* d_out, int out_size, void* d_ws, size_t ws_size,
                              hipStream_t stream) {
    const float* xyz   = (const float*)d_in[0];
    const float* rot   = (const float*)d_in[1];
    const float* verts = (const float*)d_in[2];
    const float* sw    = (const float*)d_in[3];
    const float* bt    = (const float*)d_in[4];
    float* out = (float*)d_out;

    double* bfrag = (double*)d_ws;   // (NT+NTPAD)*64 doubles = 225 KB
    prep_frags_k<<<((NT + NTPAD) * 64 + 255) / 256, 256, 0, stream>>>(verts, bfrag);
    smplnn_main<<<NBLK, 256, 0, stream>>>(xyz, rot, bfrag, sw, bt, out);
}

// Round 8
// 120.858 us; speedup vs baseline: 1.1382x; 1.1382x over previous
//
#include <hip/hip_runtime.h>
#include <math.h>

#define NPTS 65536
#define NV 6890
#define NT 432               // vertex tiles of 16 (432*16 = 6912 >= 6890)
#define NTPAD 8              // sentinel tiles appended for unclamped prefetch
#define VSPLIT 4             // waves per block, splitting the vertex range
#define TILES_PER_WAVE (NT / VSPLIT)   // 108
#define NJ 24
#define PTS_PER_BLK 64       // 64 points per block; each wave computes all 64
#define NBLK (NPTS / PTS_PER_BLK)      // 1024

typedef double f64x4 __attribute__((ext_vector_type(4)));

// Prep: pack the B-fragment stream for v_mfma_f64_16x16x4_f64.
// frag[t*64 + l] = component (l>>4) of vertex (t*16 + (l&15));
// components: 0..2 = x,y,z (f64), 3 = ||v||^2 (exact f64 from f32 coords).
// Sentinel verts (j >= NV, incl. pad tiles): (0,0,0,1e300) -> never selected.
__global__ void prep_frags_k(const float* __restrict__ verts, double* __restrict__ bf) {
    int e = blockIdx.x * blockDim.x + threadIdx.x;
    if (e >= (NT + NTPAD) * 64) return;
    int l = e & 63;
    int t = e >> 6;
    int j = t * 16 + (l & 15);
    int k = l >> 4;
    double val;
    if (j < NV) {
        if (k < 3) {
            val = (double)verts[3 * j + k];
        } else {
            double x = (double)verts[3 * j + 0];
            double y = (double)verts[3 * j + 1];
            double z = (double)verts[3 * j + 2];
            val = x * x + y * y + z * z;
        }
    } else {
        val = (k == 3) ? 1e300 : 0.0;
    }
    bf[e] = val;
}

// Pack a 13-bit global vertex index (tile<<4 | col) into the low mantissa
// bits of the f64 score. Perturbation <= 2^13 ulp (~1e-12 rel) << NN gap
// (~1e-3): ordering-safe. Min of packed values == packed min, and exact
// ties resolve to the smallest vertex index (numpy first-occurrence).
__device__ __forceinline__ double packdx(double d, unsigned orv) {
    unsigned long long u = __double_as_longlong(d);
    u = (u & ~0x1FFFULL) | (unsigned long long)orv;
    return __longlong_as_double(u);
}

__launch_bounds__(256)
__global__ void smplnn_main(const float* __restrict__ xyz,
                            const float* __restrict__ rot,
                            const double* __restrict__ bf,
                            const float* __restrict__ sw,
                            const float* __restrict__ bt,
                            float* __restrict__ out) {
    // packed-score boards: [wave][frag][row][col]
    __shared__ double smin[VSPLIT][4][16][16];

    const int tid  = threadIdx.x;
    const int lane = tid & 63;
    const int wave = tid >> 6;         // vertex-split id
    const int r = lane & 15;           // M/N index within fragment
    const int k = lane >> 4;           // K index (0..3)
    const int pbase = blockIdx.x * PTS_PER_BLK;

    // A fragments: 4 groups of 16 points (same 64 points for all 4 waves).
    // A[i][k] = (-2x_i, -2y_i, -2z_i, 1.0), i = lane&15
    double a0 = (k == 3) ? 1.0 : -2.0 * (double)xyz[3 * (pbase +      r) + k];
    double a1 = (k == 3) ? 1.0 : -2.0 * (double)xyz[3 * (pbase + 16 + r) + k];
    double a2 = (k == 3) ? 1.0 : -2.0 * (double)xyz[3 * (pbase + 32 + r) + k];
    double a3 = (k == 3) ? 1.0 : -2.0 * (double)xyz[3 * (pbase + 48 + r) + k];

    const f64x4 zero = {0.0, 0.0, 0.0, 0.0};

    // Layout self-calibration: D = row-index and D = col-index, so the
    // (lane,reg)->(row,col) mapping of the D fragment never has to be assumed.
    double ar  = (k == 3) ? (double)r : 0.0;  // A[i][3] = i  /  B[3][j] = j
    double one = (k == 3) ? 1.0 : 0.0;        // A[i][3] = 1  /  B[3][j] = 1
    f64x4 drow = __builtin_amdgcn_mfma_f64_16x16x4f64(ar, one, zero, 0, 0, 0);
    f64x4 dcol = __builtin_amdgcn_mfma_f64_16x16x4f64(one, ar, zero, 0, 0, 0);
    int rowid[4];
    unsigned colb[4];
    #pragma unroll
    for (int v = 0; v < 4; ++v) { rowid[v] = (int)drow[v]; colb[v] = (unsigned)(int)dcol[v]; }

    double m0[4], m1[4], m2[4], m3[4];
    #pragma unroll
    for (int v = 0; v < 4; ++v) { m0[v] = 1e301; m1[v] = 1e301; m2[v] = 1e301; m3[v] = 1e301; }

    // scan my quarter of the tiles: s = -2 x.v + ||v||^2, exact f64 MFMA.
    // 2-tile-deep software pipeline (~512 matrix-cycles of lookahead).
    const int tbase = wave * TILES_PER_WAVE;
    const double* bl = bf + (size_t)tbase * 64 + lane;
    double b0 = bl[0];
    double b1 = bl[64];
    for (int t = 0; t < TILES_PER_WAVE; t += 2) {
        double p0 = bl[(size_t)(t + 2) * 64];   // pad tiles are sentinels
        double p1 = bl[(size_t)(t + 3) * 64];
        {
            const unsigned tb = (unsigned)((tbase + t) << 4);
            f64x4 d0 = __builtin_amdgcn_mfma_f64_16x16x4f64(a0, b0, zero, 0, 0, 0);
            f64x4 d1 = __builtin_amdgcn_mfma_f64_16x16x4f64(a1, b0, zero, 0, 0, 0);
            f64x4 d2 = __builtin_amdgcn_mfma_f64_16x16x4f64(a2, b0, zero, 0, 0, 0);
            f64x4 d3 = __builtin_amdgcn_mfma_f64_16x16x4f64(a3, b0, zero, 0, 0, 0);
            #pragma unroll
            for (int v = 0; v < 4; ++v) {
                const unsigned orv = tb | colb[v];
                m0[v] = fmin(m0[v], packdx(d0[v], orv));
                m1[v] = fmin(m1[v], packdx(d1[v], orv));
                m2[v] = fmin(m2[v], packdx(d2[v], orv));
                m3[v] = fmin(m3[v], packdx(d3[v], orv));
            }
        }
        {
            const unsigned tb = (unsigned)((tbase + t + 1) << 4);
            f64x4 d0 = __builtin_amdgcn_mfma_f64_16x16x4f64(a0, b1, zero, 0, 0, 0);
            f64x4 d1 = __builtin_amdgcn_mfma_f64_16x16x4f64(a1, b1, zero, 0, 0, 0);
            f64x4 d2 = __builtin_amdgcn_mfma_f64_16x16x4f64(a2, b1, zero, 0, 0, 0);
            f64x4 d3 = __builtin_amdgcn_mfma_f64_16x16x4f64(a3, b1, zero, 0, 0, 0);
            #pragma unroll
            for (int v = 0; v < 4; ++v) {
                const unsigned orv = tb | colb[v];
                m0[v] = fmin(m0[v], packdx(d0[v], orv));
                m1[v] = fmin(m1[v], packdx(d1[v], orv));
                m2[v] = fmin(m2[v], packdx(d2[v], orv));
                m3[v] = fmin(m3[v], packdx(d3[v], orv));
            }
        }
        b0 = p0;
        b1 = p1;
    }

    // publish packed slots
    #pragma unroll
    for (int v = 0; v < 4; ++v) {
        smin[wave][0][rowid[v]][colb[v]] = m0[v];
        smin[wave][1][rowid[v]][colb[v]] = m1[v];
        smin[wave][2][rowid[v]][colb[v]] = m2[v];
        smin[wave][3][rowid[v]][colb[v]] = m3[v];
    }
    __syncthreads();

    // epilogue: wave 0, 64 lanes = 64 points (frag = lane>>4, row = lane&15)
    if (wave != 0) return;
    const int set = lane >> 4;
    const int row = lane & 15;
    const int i = pbase + lane;

    // pure-min merge of 4 wave-boards x 16 cols; index decodes from mantissa
    double best = 1e302;
    #pragma unroll
    for (int w = 0; w < VSPLIT; ++w) {
        #pragma unroll
        for (int c = 0; c < 16; ++c) {
            best = fmin(best, smin[w][set][row][c]);
        }
    }
    const int bi = (int)(__double_as_longlong(best) & 0x1FFFULL);  // tile*16+col

    const float xf = xyz[3 * i + 0];
    const float yf = xyz[3 * i + 1];
    const float zf = xyz[3 * i + 2];

    // T_fwd = W[bi] @ bone_transforms(24x16)
    const float* W = &sw[bi * NJ];
    float Tm[16];
    #pragma unroll
    for (int q = 0; q < 16; ++q) Tm[q] = 0.0f;
    #pragma unroll
    for (int kk = 0; kk < NJ; ++kk) {
        float w = W[kk];
        #pragma unroll
        for (int q = 0; q < 16; ++q) Tm[q] = fmaf(w, bt[16 * kk + q], Tm[q]);
    }

    // x_bar = T[:3,:3] @ x + T[:3,3]
    float xb0 = Tm[0] * xf + Tm[1] * yf + Tm[2]  * zf + Tm[3];
    float xb1 = Tm[4] * xf + Tm[5] * yf + Tm[6]  * zf + Tm[7];
    float xb2 = Tm[8] * xf + Tm[9] * yf + Tm[10] * zf + Tm[11];

    // rotation_hat from quaternion (r,x,y,z), normalized
    float qr = rot[4 * i + 0];
    float qx = rot[4 * i + 1];
    float qy = rot[4 * i + 2];
    float qz = rot[4 * i + 3];
    float inv = 1.0f / sqrtf(qr * qr + qx * qx + qy * qy + qz * qz);
    qr *= inv; qx *= inv; qy *= inv; qz *= inv;

    float Rh[9];
    Rh[0] = 1.0f - 2.0f * (qy * qy + qz * qz);
    Rh[1] = 2.0f * (qx * qy - qr * qz);
    Rh[2] = 2.0f * (qx * qz + qr * qy);
    Rh[3] = 2.0f * (qx * qy + qr * qz);
    Rh[4] = 1.0f - 2.0f * (qx * qx + qz * qz);
    Rh[5] = 2.0f * (qy * qz - qr * qx);
    Rh[6] = 2.0f * (qx * qz - qr * qy);
    Rh[7] = 2.0f * (qy * qz + qr * qx);
    Rh[8] = 1.0f - 2.0f * (qx * qx + qy * qy);

    // rotation_bar = T[:3,:3] @ Rh
    float RB[9];
    #pragma unroll
    for (int rr = 0; rr < 3; ++rr) {
        #pragma unroll
        for (int cc = 0; cc < 3; ++cc) {
            RB[3 * rr + cc] = Tm[4 * rr + 0] * Rh[cc]
                            + Tm[4 * rr + 1] * Rh[3 + cc]
                            + Tm[4 * rr + 2] * Rh[6 + cc];
        }
    }

    // outputs: x_bar [NPTS*3] | rotation_bar [NPTS*9] | T_fwd [NPTS*16]
    out[3 * i + 0] = xb0;
    out[3 * i + 1] = xb1;
    out[3 * i + 2] = xb2;
    float* ob = out + 3 * NPTS + 9 * i;
    #pragma unroll
    for (int q = 0; q < 9; ++q) ob[q] = RB[q];
    float* ot = out + 12 * NPTS + 16 * i;
    #pragma unroll
    for (int q = 0; q < 16; ++q) ot[q] = Tm[q];
}

extern "C" void kernel_launch(void* const* d_in, const int* in_sizes, int n_in,
                              void* d_out, int out_size, void* d_ws, size_t ws_size,
                              hipStream_t stream) {
    const float* xyz   = (const float*)d_in[0];
    const float* rot   = (const float*)d_in[1];
    const float* verts = (const float*)d_in[2];
    const float* sw    = (const float*)d_in[3];
    const float* bt    = (const float*)d_in[4];
    float* out = (float*)d_out;

    double* bfrag = (double*)d_ws;   // (NT+NTPAD)*64 doubles = 225 KB
    prep_frags_k<<<((NT + NTPAD) * 64 + 255) / 256, 256, 0, stream>>>(verts, bfrag);
    smplnn_main<<<NBLK, 256, 0, stream>>>(xyz, rot, bfrag, sw, bt, out);
}